// Round 1
// baseline (465.253 us; speedup 1.0000x reference)
//
#include <hip/hip_runtime.h>
#include <hip/hip_bf16.h>

#define INFEAT 4096
#define OUTFEAT 11008
#define TOKENS 2048

typedef __bf16 bf16_t;
typedef bf16_t bf16x4 __attribute__((ext_vector_type(4)));
typedef bf16_t bf16x8 __attribute__((ext_vector_type(8)));
typedef float f32x4 __attribute__((ext_vector_type(4)));

#define BM 128
#define BN 128
#define BK 64
#define LDSS 72   // LDS leading-dim stride in bf16 elems (144 B: 16B-aligned, pad breaks 32-bank stride)

__global__ __launch_bounds__(256) void q3gemm(
    const float* __restrict__ x, const unsigned int* __restrict__ qw,
    const float* __restrict__ scales, const int* __restrict__ zeros,
    const float* __restrict__ bias, float* __restrict__ out)
{
    __shared__ bf16_t Als[BM * LDSS];   // Als[m][k]  (x tile, bf16)
    __shared__ bf16_t Bls[BN * LDSS];   // Bls[n][k]  (dequant W tile, bf16; k contiguous)

    const int tid = threadIdx.x;
    const int m0 = blockIdx.y * BM;
    const int n0 = blockIdx.x * BN;

    // ---- B staging setup: thread owns column (n0 + bcol), covers 2 packed rows / pass
    const int bcol = tid & 127;     // 0..127
    const int bpr  = tid >> 7;      // 0..1
    const float scf = scales[n0 + bcol];
    const float nzs = (float)zeros[n0 + bcol] * scf;   // val = b*scf - nzs

    // ---- A staging setup: 16 float4 per row of 64 floats; 16 rows per pass, 8 passes
    const int acolg = tid & 15;
    const int arow0 = tid >> 4;

    // ---- wave/lane decomposition: 4 waves in 2x2, each computes 64x64
    const int wid  = tid >> 6;
    const int lane = tid & 63;
    const int wm = (wid & 1) * 64;
    const int wn = (wid >> 1) * 64;
    const int lr = lane & 15;   // row (A frag) / col (B frag, C/D col)
    const int lq = lane >> 4;   // quad: k-chunk for A/B frags, row-group for C/D

    f32x4 acc[4][4];
    #pragma unroll
    for (int i = 0; i < 4; ++i)
        #pragma unroll
        for (int j = 0; j < 4; ++j)
            acc[i][j] = (f32x4)0.0f;

    for (int kt = 0; kt < INFEAT / BK; ++kt) {
        const int k0 = kt * BK;

        // stage A: x[m0..+128][k0..+64] fp32 -> bf16 LDS
        #pragma unroll
        for (int p = 0; p < 8; ++p) {
            const int row = arow0 + p * 16;
            const float4 v = *(const float4*)&x[(size_t)(m0 + row) * INFEAT + k0 + acolg * 4];
            bf16x4 b;
            b[0] = (bf16_t)v.x; b[1] = (bf16_t)v.y; b[2] = (bf16_t)v.z; b[3] = (bf16_t)v.w;
            *(bf16x4*)&Als[row * LDSS + acolg * 4] = b;
        }

        // stage B: qw[k0/4 .. +16][n0..+128] -> dequant bf16 -> Bls[col][k]
        const int kp0 = k0 >> 2;
        #pragma unroll
        for (int it = 0; it < 8; ++it) {
            const int prel = it * 2 + bpr;   // 0..15 packed row within tile
            const unsigned int q = qw[(size_t)(kp0 + prel) * OUTFEAT + n0 + bcol];
            bf16x4 b;
            b[0] = (bf16_t)((float)(q & 0xFFu)        * scf - nzs);
            b[1] = (bf16_t)((float)((q >> 8) & 0xFFu) * scf - nzs);
            b[2] = (bf16_t)((float)((q >> 16) & 0xFFu)* scf - nzs);
            b[3] = (bf16_t)((float)(q >> 24)          * scf - nzs);
            *(bf16x4*)&Bls[bcol * LDSS + prel * 4] = b;
        }

        __syncthreads();

        #pragma unroll
        for (int ks = 0; ks < 2; ++ks) {
            bf16x8 af[4], bfv[4];
            #pragma unroll
            for (int t = 0; t < 4; ++t) {
                af[t]  = *(const bf16x8*)&Als[(wm + t * 16 + lr) * LDSS + ks * 32 + lq * 8];
                bfv[t] = *(const bf16x8*)&Bls[(wn + t * 16 + lr) * LDSS + ks * 32 + lq * 8];
            }
            #pragma unroll
            for (int i = 0; i < 4; ++i)
                #pragma unroll
                for (int j = 0; j < 4; ++j)
                    acc[i][j] = __builtin_amdgcn_mfma_f32_16x16x32_bf16(af[i], bfv[j], acc[i][j], 0, 0, 0);
        }

        __syncthreads();
    }

    // epilogue: C/D layout col=lane&15, row=(lane>>4)*4+reg
    #pragma unroll
    for (int j = 0; j < 4; ++j) {
        const int col = n0 + wn + j * 16 + lr;
        const float bv = bias[col];
        #pragma unroll
        for (int i = 0; i < 4; ++i) {
            const int rbase = m0 + wm + i * 16 + lq * 4;
            #pragma unroll
            for (int r = 0; r < 4; ++r) {
                out[(size_t)(rbase + r) * OUTFEAT + col] = acc[i][j][r] + bv;
            }
        }
    }
}

extern "C" void kernel_launch(void* const* d_in, const int* in_sizes, int n_in,
                              void* d_out, int out_size, void* d_ws, size_t ws_size,
                              hipStream_t stream) {
    const float*        x      = (const float*)d_in[0];
    const unsigned int* qw     = (const unsigned int*)d_in[1];
    const float*        scales = (const float*)d_in[2];
    const int*          zeros  = (const int*)d_in[3];
    const float*        bias   = (const float*)d_in[4];
    float*              out    = (float*)d_out;

    dim3 grid(OUTFEAT / BN, TOKENS / BM);   // 86 x 16
    q3gemm<<<grid, dim3(256), 0, stream>>>(x, qw, scales, zeros, bias, out);
}

// Round 2
// 403.702 us; speedup vs baseline: 1.1525x; 1.1525x over previous
//
#include <hip/hip_runtime.h>
#include <hip/hip_bf16.h>

#define INFEAT 4096
#define OUTFEAT 11008
#define TOKENS 2048

typedef __bf16 bf16_t;
typedef bf16_t bf16x4 __attribute__((ext_vector_type(4)));
typedef bf16_t bf16x8 __attribute__((ext_vector_type(8)));
typedef float f32x4 __attribute__((ext_vector_type(4)));

#define BM 128
#define BN 128
#define BK 64

__device__ __forceinline__ void async_copy16(const bf16_t* g, bf16_t* l) {
    __builtin_amdgcn_global_load_lds((const __attribute__((address_space(1))) void*)g,
                                     (__attribute__((address_space(3))) void*)l,
                                     16, 0, 0);
}

// ---------------- pre-pass 1: x fp32 -> bf16 (same layout) ----------------
__global__ __launch_bounds__(256) void cvt_x(const float* __restrict__ x, bf16_t* __restrict__ xb) {
    size_t i = ((size_t)blockIdx.x * 256 + threadIdx.x) * 8;
    float4 a = *(const float4*)&x[i];
    float4 b = *(const float4*)&x[i + 4];
    bf16x8 o;
    o[0] = (bf16_t)a.x; o[1] = (bf16_t)a.y; o[2] = (bf16_t)a.z; o[3] = (bf16_t)a.w;
    o[4] = (bf16_t)b.x; o[5] = (bf16_t)b.y; o[6] = (bf16_t)b.z; o[7] = (bf16_t)b.w;
    *(bf16x8*)&xb[i] = o;
}

// ------- pre-pass 2: dequant W and transpose -> bw[n][k] (bf16) ----------
// qw: [INFEAT/4][OUTFEAT] packed uint32 (4 k-bytes per word).
// Tile: 64 packed-rows (256 k) x 64 n per block, LDS transpose.
__global__ __launch_bounds__(256) void deq_w(
    const unsigned int* __restrict__ qw, const float* __restrict__ scales,
    const int* __restrict__ zeros, bf16_t* __restrict__ bw)
{
    __shared__ bf16_t T[64][264];   // [n][k_local], stride 264 (528B, 16B-aligned)
    const int n0 = blockIdx.x * 64;
    const int kp0 = blockIdx.y * 64;
    const int tn = threadIdx.x & 63;
    const int tk4 = threadIdx.x >> 6;   // 0..3

    const float sc = scales[n0 + tn];
    const float zs = (float)zeros[n0 + tn] * sc;

    #pragma unroll
    for (int it = 0; it < 16; ++it) {
        const int kp = tk4 * 16 + it;
        const unsigned int q = qw[(size_t)(kp0 + kp) * OUTFEAT + n0 + tn];
        bf16x4 v;
        v[0] = (bf16_t)((float)(q & 0xFFu)         * sc - zs);
        v[1] = (bf16_t)((float)((q >> 8) & 0xFFu)  * sc - zs);
        v[2] = (bf16_t)((float)((q >> 16) & 0xFFu) * sc - zs);
        v[3] = (bf16_t)((float)(q >> 24)           * sc - zs);
        *(bf16x4*)&T[tn][kp * 4] = v;
    }
    __syncthreads();

    #pragma unroll
    for (int i = 0; i < 8; ++i) {
        const int flat = i * 256 + threadIdx.x;
        const int n = flat >> 5;        // 0..63
        const int c = flat & 31;        // 16B chunk within 512B row
        bf16x8 v = *(const bf16x8*)&T[n][c * 8];
        *(bf16x8*)&bw[(size_t)(n0 + n) * INFEAT + kp0 * 4 + c * 8] = v;
    }
}

// ---------------- main GEMM: m97 structure, global_load_lds, XOR swizzle ----
// LDS tile layout: row r (128), 8 chunks of 8 bf16; chunk kg stored at slot
// p = kg ^ (r&7)  =>  fragment ds_read_b128 is perfectly bank-balanced.
__global__ __launch_bounds__(256) void q3gemm_bf16(
    const bf16_t* __restrict__ xb, const bf16_t* __restrict__ bwt,
    const float* __restrict__ bias, float* __restrict__ out)
{
    __shared__ bf16_t Als[BM * BK];   // 16 KB
    __shared__ bf16_t Bls[BN * BK];   // 16 KB

    const int tid = threadIdx.x;
    const int m0 = blockIdx.y * BM;
    const int n0 = blockIdx.x * BN;

    const int wid  = tid >> 6;
    const int lane = tid & 63;
    const int wm = (wid & 1) * 64;
    const int wn = (wid >> 1) * 64;
    const int lr = lane & 15;
    const int lq = lane >> 4;

    // staging decomposition: per (wave, j): 64 lanes x 16B = 8 rows
    const int rbase[4] = { (wid*4+0)*8, (wid*4+1)*8, (wid*4+2)*8, (wid*4+3)*8 };
    const int rsub = lane >> 3;          // 0..7
    const int s_swz = (lane & 7);        // slot p = lane&7 -> source chunk s = p ^ (r&7)

    f32x4 acc[4][4];
    #pragma unroll
    for (int i = 0; i < 4; ++i)
        #pragma unroll
        for (int j = 0; j < 4; ++j)
            acc[i][j] = (f32x4)0.0f;

    for (int kt = 0; kt < INFEAT / BK; ++kt) {
        const int k0 = kt * BK;

        #pragma unroll
        for (int j = 0; j < 4; ++j) {
            const int r = rbase[j] + rsub;
            const int s = s_swz ^ (r & 7);
            async_copy16(&xb[(size_t)(m0 + r) * INFEAT + k0 + s * 8], &Als[rbase[j] * 64]);
        }
        #pragma unroll
        for (int j = 0; j < 4; ++j) {
            const int r = rbase[j] + rsub;
            const int s = s_swz ^ (r & 7);
            async_copy16(&bwt[(size_t)(n0 + r) * INFEAT + k0 + s * 8], &Bls[rbase[j] * 64]);
        }

        __syncthreads();

        #pragma unroll
        for (int ks = 0; ks < 2; ++ks) {
            bf16x8 af[4], bfv[4];
            #pragma unroll
            for (int t = 0; t < 4; ++t) {
                const int ra = wm + t * 16 + lr;
                const int pa = (ks * 4 + lq) ^ (ra & 7);
                af[t] = *(const bf16x8*)&Als[ra * 64 + pa * 8];
                const int rb = wn + t * 16 + lr;
                const int pb = (ks * 4 + lq) ^ (rb & 7);
                bfv[t] = *(const bf16x8*)&Bls[rb * 64 + pb * 8];
            }
            #pragma unroll
            for (int i = 0; i < 4; ++i)
                #pragma unroll
                for (int j = 0; j < 4; ++j)
                    acc[i][j] = __builtin_amdgcn_mfma_f32_16x16x32_bf16(af[i], bfv[j], acc[i][j], 0, 0, 0);
        }

        __syncthreads();
    }

    #pragma unroll
    for (int j = 0; j < 4; ++j) {
        const int col = n0 + wn + j * 16 + lr;
        const float bv = bias[col];
        #pragma unroll
        for (int i = 0; i < 4; ++i) {
            const int rb = m0 + wm + i * 16 + lq * 4;
            #pragma unroll
            for (int r = 0; r < 4; ++r)
                out[(size_t)(rb + r) * OUTFEAT + col] = acc[i][j][r] + bv;
        }
    }
}

// ---------------- fallback (round-1 kernel, used if ws too small) ----------
#define LDSS 72
__global__ __launch_bounds__(256) void q3gemm_fb(
    const float* __restrict__ x, const unsigned int* __restrict__ qw,
    const float* __restrict__ scales, const int* __restrict__ zeros,
    const float* __restrict__ bias, float* __restrict__ out)
{
    __shared__ bf16_t Als[BM * LDSS];
    __shared__ bf16_t Bls[BN * LDSS];
    const int tid = threadIdx.x;
    const int m0 = blockIdx.y * BM;
    const int n0 = blockIdx.x * BN;
    const int bcol = tid & 127;
    const int bpr  = tid >> 7;
    const float scf = scales[n0 + bcol];
    const float nzs = (float)zeros[n0 + bcol] * scf;
    const int acolg = tid & 15;
    const int arow0 = tid >> 4;
    const int wid  = tid >> 6;
    const int lane = tid & 63;
    const int wm = (wid & 1) * 64;
    const int wn = (wid >> 1) * 64;
    const int lr = lane & 15;
    const int lq = lane >> 4;
    f32x4 acc[4][4];
    #pragma unroll
    for (int i = 0; i < 4; ++i)
        #pragma unroll
        for (int j = 0; j < 4; ++j) acc[i][j] = (f32x4)0.0f;
    for (int kt = 0; kt < INFEAT / BK; ++kt) {
        const int k0 = kt * BK;
        #pragma unroll
        for (int p = 0; p < 8; ++p) {
            const int row = arow0 + p * 16;
            const float4 v = *(const float4*)&x[(size_t)(m0 + row) * INFEAT + k0 + acolg * 4];
            bf16x4 b;
            b[0] = (bf16_t)v.x; b[1] = (bf16_t)v.y; b[2] = (bf16_t)v.z; b[3] = (bf16_t)v.w;
            *(bf16x4*)&Als[row * LDSS + acolg * 4] = b;
        }
        const int kp0 = k0 >> 2;
        #pragma unroll
        for (int it = 0; it < 8; ++it) {
            const int prel = it * 2 + bpr;
            const unsigned int q = qw[(size_t)(kp0 + prel) * OUTFEAT + n0 + bcol];
            bf16x4 b;
            b[0] = (bf16_t)((float)(q & 0xFFu)        * scf - nzs);
            b[1] = (bf16_t)((float)((q >> 8) & 0xFFu) * scf - nzs);
            b[2] = (bf16_t)((float)((q >> 16) & 0xFFu)* scf - nzs);
            b[3] = (bf16_t)((float)(q >> 24)          * scf - nzs);
            *(bf16x4*)&Bls[bcol * LDSS + prel * 4] = b;
        }
        __syncthreads();
        #pragma unroll
        for (int ks = 0; ks < 2; ++ks) {
            bf16x8 af[4], bfv[4];
            #pragma unroll
            for (int t = 0; t < 4; ++t) {
                af[t]  = *(const bf16x8*)&Als[(wm + t * 16 + lr) * LDSS + ks * 32 + lq * 8];
                bfv[t] = *(const bf16x8*)&Bls[(wn + t * 16 + lr) * LDSS + ks * 32 + lq * 8];
            }
            #pragma unroll
            for (int i = 0; i < 4; ++i)
                #pragma unroll
                for (int j = 0; j < 4; ++j)
                    acc[i][j] = __builtin_amdgcn_mfma_f32_16x16x32_bf16(af[i], bfv[j], acc[i][j], 0, 0, 0);
        }
        __syncthreads();
    }
    #pragma unroll
    for (int j = 0; j < 4; ++j) {
        const int col = n0 + wn + j * 16 + lr;
        const float bv = bias[col];
        #pragma unroll
        for (int i = 0; i < 4; ++i) {
            const int rbs = m0 + wm + i * 16 + lq * 4;
            #pragma unroll
            for (int r = 0; r < 4; ++r)
                out[(size_t)(rbs + r) * OUTFEAT + col] = acc[i][j][r] + bv;
        }
    }
}

extern "C" void kernel_launch(void* const* d_in, const int* in_sizes, int n_in,
                              void* d_out, int out_size, void* d_ws, size_t ws_size,
                              hipStream_t stream) {
    const float*        x      = (const float*)d_in[0];
    const unsigned int* qw     = (const unsigned int*)d_in[1];
    const float*        scales = (const float*)d_in[2];
    const int*          zeros  = (const int*)d_in[3];
    const float*        bias   = (const float*)d_in[4];
    float*              out    = (float*)d_out;

    const size_t bw_bytes = (size_t)OUTFEAT * INFEAT * sizeof(bf16_t);   // 90.2 MB
    const size_t xb_bytes = (size_t)TOKENS * INFEAT * sizeof(bf16_t);    // 16.8 MB

    if (ws_size >= bw_bytes + xb_bytes) {
        bf16_t* bw = (bf16_t*)d_ws;
        bf16_t* xb = (bf16_t*)((char*)d_ws + bw_bytes);

        cvt_x<<<dim3((TOKENS * INFEAT) / (256 * 8)), dim3(256), 0, stream>>>(x, xb);
        deq_w<<<dim3(OUTFEAT / 64, (INFEAT / 4) / 64), dim3(256), 0, stream>>>(qw, scales, zeros, bw);
        q3gemm_bf16<<<dim3(OUTFEAT / BN, TOKENS / BM), dim3(256), 0, stream>>>(xb, bw, bias, out);
    } else {
        q3gemm_fb<<<dim3(OUTFEAT / BN, TOKENS / BM), dim3(256), 0, stream>>>(x, qw, scales, zeros, bias, out);
    }
}